// Round 1
// baseline (1423.098 us; speedup 1.0000x reference)
//
#include <hip/hip_runtime.h>
#include <math.h>

// Gradient clipping: global L2 norm over 5 fp32 tensors, then scale all.
// Memory-bound. Structural floor: read 810MB (norm) + read 810MB + write 810MB
// = 2.43 GB => ~390 us at 6.3 TB/s achievable.
//
// v2 changes vs 1434us baseline:
//  - reduce: fp32 quad accumulators (kills the serial fp64 add chain that
//    throttled load issue; f64 only at per-tensor promotion + final tree)
//  - partial-sum array in ws => no memset dispatch, no fp64 atomics (3->2 launches)
//  - scale traverses in REVERSE order => reads the ~250MB L3 tail left by reduce

#define NT 5
#define BLOCK 256
#define GRID 2048

struct Args5 {
    const float4* p[NT];
    long long n4[NT];   // element count in float4 units (all sizes % 4 == 0)
};

template<bool ATOMIC>
__global__ __launch_bounds__(BLOCK, 8) void reduce_sq_kernel(Args5 args, double* partials) {
    const long long stride = (long long)GRID * BLOCK;
    const long long tid = (long long)blockIdx.x * BLOCK + threadIdx.x;

    double local = 0.0;
    #pragma unroll
    for (int t = 0; t < NT; ++t) {
        const float4* __restrict__ p = args.p[t];
        const long long n4 = args.n4[t];
        // 4 independent fp32 FMA chains: no cross-iteration serial f64 dep.
        float a0 = 0.f, a1 = 0.f, a2 = 0.f, a3 = 0.f;
        for (long long i = tid; i < n4; i += stride) {
            float4 v = p[i];
            a0 = fmaf(v.x, v.x, a0);
            a1 = fmaf(v.y, v.y, a1);
            a2 = fmaf(v.z, v.z, a2);
            a3 = fmaf(v.w, v.w, a3);
        }
        local += (double)((a0 + a1) + (a2 + a3));
    }

    // wave(64) butterfly reduce in f64
    for (int off = 32; off > 0; off >>= 1)
        local += __shfl_down(local, off, 64);

    __shared__ double smem[BLOCK / 64];
    const int lane = threadIdx.x & 63;
    const int wave = threadIdx.x >> 6;
    if (lane == 0) smem[wave] = local;
    __syncthreads();
    if (threadIdx.x == 0) {
        double s = 0.0;
        #pragma unroll
        for (int w = 0; w < BLOCK / 64; ++w) s += smem[w];
        if (ATOMIC) atomicAdd(partials, s);       // fallback path (tiny ws)
        else        partials[blockIdx.x] = s;     // no memset, no atomics
    }
}

__global__ __launch_bounds__(BLOCK, 8) void scale_kernel(Args5 args, float4* out,
                                                         const double* partials, int npart) {
    // Every block redundantly reduces the partial array (<=16KB, L2/L3-resident).
    __shared__ double smem[BLOCK / 64];
    __shared__ float sscale;
    {
        double s = 0.0;
        for (int k = threadIdx.x; k < npart; k += BLOCK) s += partials[k];
        for (int off = 32; off > 0; off >>= 1)
            s += __shfl_down(s, off, 64);
        const int lane = threadIdx.x & 63;
        const int wave = threadIdx.x >> 6;
        if (lane == 0) smem[wave] = s;
        __syncthreads();
        if (threadIdx.x == 0) {
            double tot = 0.0;
            #pragma unroll
            for (int w = 0; w < BLOCK / 64; ++w) tot += smem[w];
            const float norm = (float)sqrt(tot);
            sscale = (norm > 1.0f) ? (1.0f / (norm + 1e-6f)) : 1.0f;
        }
        __syncthreads();
    }
    const float scale = sscale;

    const long long stride = (long long)GRID * BLOCK;
    const long long tid = (long long)blockIdx.x * BLOCK + threadIdx.x;

    long long offs[NT];
    {
        long long acc = 0;
        #pragma unroll
        for (int t = 0; t < NT; ++t) { offs[t] = acc; acc += args.n4[t]; }
    }

    // Reverse traversal: the reduce kernel streamed 0..810MB forward, so L3
    // holds the tail when we start. Read tail-first for ~250MB of L3 hits.
    // Wave still touches a contiguous descending 1KB segment => coalesced.
    #pragma unroll
    for (int tt = 0; tt < NT; ++tt) {
        const int t = NT - 1 - tt;
        const float4* __restrict__ p = args.p[t];
        const long long n4 = args.n4[t];
        float4* __restrict__ o = out + offs[t];
        for (long long idx = tid; idx < n4; idx += stride) {
            const long long i = n4 - 1 - idx;
            float4 v = p[i];
            v.x *= scale; v.y *= scale; v.z *= scale; v.w *= scale;
            o[i] = v;
        }
    }
}

extern "C" void kernel_launch(void* const* d_in, const int* in_sizes, int n_in,
                              void* d_out, int out_size, void* d_ws, size_t ws_size,
                              hipStream_t stream) {
    Args5 args;
    for (int t = 0; t < NT; ++t) {
        args.p[t] = (const float4*)d_in[t];
        args.n4[t] = (long long)in_sizes[t] / 4;
    }
    double* partials = (double*)d_ws;

    if (ws_size >= (size_t)GRID * sizeof(double)) {
        // partial-sum path: ws is poisoned each call but we fully overwrite
        // partials[0..GRID) before reading them.
        reduce_sq_kernel<false><<<GRID, BLOCK, 0, stream>>>(args, partials);
        scale_kernel<<<GRID, BLOCK, 0, stream>>>(args, (float4*)d_out, partials, GRID);
    } else {
        // fallback: single-accumulator atomic path (needs zeroed acc)
        hipMemsetAsync(partials, 0, sizeof(double), stream);
        reduce_sq_kernel<true><<<GRID, BLOCK, 0, stream>>>(args, partials);
        scale_kernel<<<GRID, BLOCK, 0, stream>>>(args, (float4*)d_out, partials, 1);
    }
}